// Round 2
// baseline (6029.979 us; speedup 1.0000x reference)
//
#include <hip/hip_runtime.h>

static constexpr int T_STEPS = 512;
static constexpr int BATCH   = 64;
static constexpr int DIN     = 256;
static constexpr int HID     = 512;
static constexpr int KDIM    = DIN + HID;   // 768
static constexpr int S4      = 193;         // LDS row stride in float4 (192 data + 1 pad)
static constexpr int NBLK    = 256;
static constexpr int NPROD   = 64;          // producers (kslices) per bgroup

__device__ __forceinline__ float fast_sigmoid(float v) {
    return 1.0f / (1.0f + __expf(-v));
}
__device__ __forceinline__ float fast_tanh(float v) {
    return 1.0f - 2.0f / (__expf(2.0f * v) + 1.0f);
}

// Relaxed agent-scope ops: L1+L2 bypass, served at the device coherence
// point. No buffer_wbl2 / buffer_inv anywhere (rounds 1-3 lesson: per-WG
// full-L2 writeback+invalidate is catastrophic).
__device__ __forceinline__ void store_bypass(float* p, float v) {
    __hip_atomic_store((unsigned int*)p, __float_as_uint(v),
                       __ATOMIC_RELAXED, __HIP_MEMORY_SCOPE_AGENT);
}
__device__ __forceinline__ float load_bypass(const float* p) {
    return __uint_as_float(__hip_atomic_load((const unsigned int*)p,
                           __ATOMIC_RELAXED, __HIP_MEMORY_SCOPE_AGENT));
}
__device__ __forceinline__ void store_flag(unsigned* p, unsigned v) {
    __hip_atomic_store(p, v, __ATOMIC_RELAXED, __HIP_MEMORY_SCOPE_AGENT);
}
__device__ __forceinline__ unsigned load_flag(const unsigned* p) {
    return __hip_atomic_load(p, __ATOMIC_RELAXED, __HIP_MEMORY_SCOPE_AGENT);
}

// ROUND 7: per-producer flags (relaxed stores) + wave-wide __all poll;
//          x-part GEMM hoisted above the wait (hides in the poll slack).
// ROUND 8: h-part of W (32 float4/thread = 128 VGPRs) cached in REGISTERS
//          for all 512 steps. W is step-invariant; re-reading it from LDS
//          every step was half of all LDS traffic AND a structural 4-way
//          bank conflict (row stride 193 f4 => rows 4 apart alias 16 banks
//          apart; unfixable by padding). The critical-path h-GEMM now reads
//          only C (broadcast across rg lanes, <=2-way = free). x-part W
//          stays in LDS: its reads run in the flag-wait slack, latency-
//          hidden. All wreg indices are compile-time (full unroll).
__global__ __launch_bounds__(512, 1)
void lstm_persistent(const float* __restrict__ x,
                     const float* __restrict__ Wf, const float* __restrict__ bfp,
                     const float* __restrict__ Wi, const float* __restrict__ bip,
                     const float* __restrict__ Wg, const float* __restrict__ bgp,
                     const float* __restrict__ Wo, const float* __restrict__ bop,
                     float* __restrict__ out, unsigned* __restrict__ flag_ws) {
    __shared__ float4 W4[32 * S4];        // 32 rows x 768 fp32
    __shared__ float4 C4[16 * S4];        // combined [x|h] for 16 b
    __shared__ float  gates_s[16 * 33];
    __shared__ float  bias_s[32];

    const int tid = threadIdx.x;
    const int wg  = blockIdx.x;
    const int bgroup = (wg & 7) >> 1;                  // 0..3
    const int kslice = ((wg >> 3) << 1) | (wg & 1);    // 0..63
    const int bg0 = bgroup * 16;
    const int k0  = kslice * 8;

    // 64 flags per bgroup, packed 256 B (one wave-instruction covers all 64)
    unsigned* const flags = flag_ws + bgroup * NPROD;

    // ---- one-time: stage 32 weight rows (gate*8 + unit) into LDS ----
    {
        const int r    = tid >> 4;     // 0..31
        const int c0   = tid & 15;
        const int gate = r >> 3;
        const int unit = k0 + (r & 7);
        const float* wsrc = (gate == 0) ? Wf : (gate == 1) ? Wi : (gate == 2) ? Wg : Wo;
        const float4* src4 = (const float4*)(wsrc + (size_t)unit * KDIM);
        #pragma unroll 2
        for (int m = 0; m < 12; ++m)
            W4[r * S4 + c0 + 16 * m] = src4[c0 + 16 * m];
        if (tid < 32) {
            const int g2 = tid >> 3;
            const float* bsrc = (g2 == 0) ? bfp : (g2 == 1) ? bip : (g2 == 2) ? bgp : bop;
            bias_s[tid] = bsrc[k0 + (tid & 7)];
        }
    }

    float* const hx_sec = out + (size_t)T_STEPS * BATCH * HID;  // buf0 (ends as hx)
    float* const cx_sec = hx_sec + BATCH * HID;                 // buf1 (ends as cx)

    const int lb2 = tid >> 3;   // cell-update mapping (tid<128)
    const int u2  = tid & 7;

    // zero h0 slab via bypass stores; publish flag=1. __syncthreads drains
    // vmcnt(0) before s_barrier -> h stores visible before the flag store.
    if (tid < 128)
        store_bypass(&hx_sec[(size_t)(bg0 + lb2) * HID + (k0 + u2)], 0.0f);
    __syncthreads();     // also orders W4 staging before the wreg reads below
    if (tid == 0)
        store_flag(&flags[kslice], 1u);

    // GEMM mapping: lane strip over K (16 interleaved f4 stripes), 4x4 tile
    const int lbg = tid >> 7;        // 0..3  -> batches lbg*4..+3
    const int rg  = (tid >> 4) & 7;  // 0..7  -> rows rg*4..+3
    const int kq  = tid & 15;        // 0..15 -> K stripe

    // ---- one-time: h-part W fragments -> registers (128 VGPRs) ----
    // wreg[it*4+j] = W4[(rg*4+j)][kq + 16*(it+4)]  (K dwords 256..767)
    float4 wreg[32];
    #pragma unroll
    for (int it = 0; it < 8; ++it)
        #pragma unroll
        for (int j = 0; j < 4; ++j)
            wreg[it * 4 + j] = W4[(rg * 4 + j) * S4 + kq + 16 * (it + 4)];

    float c_reg = 0.0f;

    for (int t = 0; t < T_STEPS; ++t) {
        const float* h_read  = (t & 1) ? cx_sec : hx_sec;   // h_t in buf[t&1]
        float*       h_write = (t & 1) ? hx_sec : cx_sec;   // h_{t+1} -> buf[(t+1)&1]

        // ---- A: stage x_t (flag-independent; hides behind the poll) ----
        {
            const float4* xs = (const float4*)(x + ((size_t)t * BATCH + bg0) * DIN);
            #pragma unroll
            for (int m = 0; m < 2; ++m) {
                const int i4 = tid + 512 * m;               // 16b x 64 f4
                C4[(i4 >> 6) * S4 + (i4 & 63)] = xs[i4];
            }
        }
        __syncthreads();   // x staged; safe: previous D/E reads fenced above

        // ---- A2: x-part GEMM (K dwords 0..255) — independent of h_t ----
        // W for this part comes from LDS: these reads (and their 4-way
        // conflicts) execute in the flag-wait slack, off the critical path.
        float acc[4][4];
        #pragma unroll
        for (int i = 0; i < 4; ++i)
            #pragma unroll
            for (int j = 0; j < 4; ++j) acc[i][j] = 0.0f;

        #pragma unroll 2
        for (int it = 0; it < 4; ++it) {
            const int dq = kq + 16 * it;
            float4 cv[4], wv[4];
            #pragma unroll
            for (int i = 0; i < 4; ++i) cv[i] = C4[(lbg * 4 + i) * S4 + dq];
            #pragma unroll
            for (int j = 0; j < 4; ++j) wv[j] = W4[(rg * 4 + j) * S4 + dq];
            #pragma unroll
            for (int i = 0; i < 4; ++i) {
                #pragma unroll
                for (int j = 0; j < 4; ++j) {
                    acc[i][j] = fmaf(cv[i].x, wv[j].x, acc[i][j]);
                    acc[i][j] = fmaf(cv[i].y, wv[j].y, acc[i][j]);
                    acc[i][j] = fmaf(cv[i].z, wv[j].z, acc[i][j]);
                    acc[i][j] = fmaf(cv[i].w, wv[j].w, acc[i][j]);
                }
            }
        }

        // ---- B: wait until all 64 peers published h_t ----
        if (tid < 64) {
            const unsigned target = (unsigned)(t + 1);
            while (!__all((int)(load_flag(&flags[tid]) >= target)))
                __builtin_amdgcn_s_sleep(1);
        }
        __syncthreads();   // full barrier: gather can't hoist above

        // ---- C: gather h_t via bypass loads, full MLP (16 in flight) ----
        {
            const float* hsrc = h_read + (size_t)bg0 * HID;
            float hv[16];
            #pragma unroll
            for (int m = 0; m < 16; ++m)
                hv[m] = load_bypass(&hsrc[512 * m + tid]);
            float* Cf = (float*)C4;
            #pragma unroll
            for (int m = 0; m < 16; ++m)
                Cf[m * (S4 * 4) + 256 + tid] = hv[m];   // consecutive dwords: conflict-free
        }
        __syncthreads();

        // ---- D: h-part GEMM (K dwords 256..767) — W from REGISTERS ----
        // Only cv comes from LDS (16 distinct f4 per wave, broadcast across
        // rg => conflict-free). Full unroll keeps wreg indices static.
        #pragma unroll
        for (int it = 0; it < 8; ++it) {
            const int dq = kq + 16 * (it + 4);
            float4 cv[4];
            #pragma unroll
            for (int i = 0; i < 4; ++i) cv[i] = C4[(lbg * 4 + i) * S4 + dq];
            #pragma unroll
            for (int i = 0; i < 4; ++i) {
                #pragma unroll
                for (int j = 0; j < 4; ++j) {
                    const float4 w = wreg[it * 4 + j];
                    acc[i][j] = fmaf(cv[i].x, w.x, acc[i][j]);
                    acc[i][j] = fmaf(cv[i].y, w.y, acc[i][j]);
                    acc[i][j] = fmaf(cv[i].z, w.z, acc[i][j]);
                    acc[i][j] = fmaf(cv[i].w, w.w, acc[i][j]);
                }
            }
        }

        // ---- E: reduce 16 K-stripes via shuffle, park in LDS ----
        #pragma unroll
        for (int i = 0; i < 4; ++i) {
            #pragma unroll
            for (int j = 0; j < 4; ++j) {
                float v = acc[i][j];
                v += __shfl_xor(v, 1);
                v += __shfl_xor(v, 2);
                v += __shfl_xor(v, 4);
                v += __shfl_xor(v, 8);
                if (kq == 0)
                    gates_s[(lbg * 4 + i) * 33 + (rg * 4 + j)] = v;
            }
        }
        __syncthreads();

        // ---- F: LSTM cell update (one thread per (b, hidden unit)) ----
        if (tid < 128) {
            const float pf = gates_s[lb2 * 33 + u2]      + bias_s[u2];
            const float pi = gates_s[lb2 * 33 + 8 + u2]  + bias_s[8 + u2];
            const float pg = gates_s[lb2 * 33 + 16 + u2] + bias_s[16 + u2];
            const float po = gates_s[lb2 * 33 + 24 + u2] + bias_s[24 + u2];
            const float fg = fast_sigmoid(pf);
            const float ig = fast_sigmoid(pi);
            const float gg = fast_tanh(pg);
            const float og = fast_sigmoid(po);
            c_reg = fg * c_reg + ig * gg;
            const float h = og * fast_tanh(c_reg);
            const int b = bg0 + lb2;
            const int k = k0 + u2;
            store_bypass(&h_write[(size_t)b * HID + k], h);   // coherent-direct
            out[((size_t)t * BATCH + b) * HID + k] = h;       // cached, flushed at end
        }
        __syncthreads();   // drains vmcnt(0): h bypass stores globally visible

        // ---- G: publish h_{t+1}: one relaxed store, no RMW ----
        if (tid == 0)
            store_flag(&flags[kslice], (unsigned)(t + 2));
    }

    // Final: hx (h_512) already in hx_sec. Overwrite buf1 (h_511) with c only
    // after all peers finished step 511 (flag = 513 => done reading h_511).
    if (tid < 64) {
        const unsigned target = (unsigned)(T_STEPS + 1);
        while (!__all((int)(load_flag(&flags[tid]) >= target)))
            __builtin_amdgcn_s_sleep(1);
    }
    __syncthreads();
    if (tid < 128)
        cx_sec[(size_t)(bg0 + lb2) * HID + (k0 + u2)] = c_reg;
}

extern "C" void kernel_launch(void* const* d_in, const int* in_sizes, int n_in,
                              void* d_out, int out_size, void* d_ws, size_t ws_size,
                              hipStream_t stream) {
    (void)in_sizes; (void)n_in; (void)ws_size; (void)out_size;
    const float* x  = (const float*)d_in[0];
    const float* Wf = (const float*)d_in[1];
    const float* bf = (const float*)d_in[2];
    const float* Wi = (const float*)d_in[3];
    const float* bi = (const float*)d_in[4];
    const float* Wg = (const float*)d_in[5];
    const float* bg = (const float*)d_in[6];
    const float* Wo = (const float*)d_in[7];
    const float* bo = (const float*)d_in[8];
    float* out = (float*)d_out;
    unsigned* flags = (unsigned*)d_ws;

    // flags[4 bgroups][64 producers], 4B each; must start 0 (d_ws poisoned)
    hipMemsetAsync(d_ws, 0, 4 * NPROD * sizeof(unsigned), stream);

    void* args[] = {&x, &Wf, &bf, &Wi, &bi, &Wg, &bg, &Wo, &bo, &out, &flags};
    hipLaunchCooperativeKernel(reinterpret_cast<void*>(lstm_persistent),
                               dim3(NBLK), dim3(512), args, 0, stream);
}

// Round 3
// 5991.227 us; speedup vs baseline: 1.0065x; 1.0065x over previous
//
#include <hip/hip_runtime.h>

static constexpr int T_STEPS = 512;
static constexpr int BATCH   = 64;
static constexpr int DIN     = 256;
static constexpr int HID     = 512;
static constexpr int KDIM    = DIN + HID;   // 768
static constexpr int S4      = 193;         // LDS row stride in float4 (192 data + 1 pad)
static constexpr int NBLK    = 256;
static constexpr int NPROD   = 64;          // producers (kslices) per bgroup

__device__ __forceinline__ float fast_sigmoid(float v) {
    return 1.0f / (1.0f + __expf(-v));
}
__device__ __forceinline__ float fast_tanh(float v) {
    return 1.0f - 2.0f / (__expf(2.0f * v) + 1.0f);
}

// Relaxed agent-scope ops: L1+L2 bypass, served at the device coherence
// point. No buffer_wbl2 / buffer_inv anywhere (rounds 1-3 lesson: per-WG
// full-L2 writeback+invalidate is catastrophic).
__device__ __forceinline__ void store_bypass(float* p, float v) {
    __hip_atomic_store((unsigned int*)p, __float_as_uint(v),
                       __ATOMIC_RELAXED, __HIP_MEMORY_SCOPE_AGENT);
}
__device__ __forceinline__ float load_bypass(const float* p) {
    return __uint_as_float(__hip_atomic_load((const unsigned int*)p,
                           __ATOMIC_RELAXED, __HIP_MEMORY_SCOPE_AGENT));
}
__device__ __forceinline__ void store_flag(unsigned* p, unsigned v) {
    __hip_atomic_store(p, v, __ATOMIC_RELAXED, __HIP_MEMORY_SCOPE_AGENT);
}
__device__ __forceinline__ unsigned load_flag(const unsigned* p) {
    return __hip_atomic_load(p, __ATOMIC_RELAXED, __HIP_MEMORY_SCOPE_AGENT);
}

// ROUND 7: per-producer flags (relaxed stores) + wave-wide __all poll;
//          x-part GEMM hoisted above the wait (hides in the poll slack).
// ROUND 8: h-part W cached in registers -> REGRESSED (6030us): compiler's
//          default occupancy heuristic capped VGPR at 128 and spilled the
//          128-VGPR wreg array to scratch (VGPR_Count=128, WRITE_SIZE
//          135->295MB, scratch reads on the critical path every step).
// ROUND 9: pin the allocator with amdgpu_waves_per_eu(2,2). Our geometry is
//          fixed at 8 waves/CU = 2 waves/EU (persistent 1 WG/CU), so VGPR
//          cap rises to 256 with ZERO occupancy cost. Live set ~195 VGPRs:
//          wreg 128 + acc 16 + A2 transients 32 + addressing ~20.
//          W is step-invariant; keeping the h-part in registers removes
//          half of all LDS traffic AND the structural 4-way bank conflict
//          (row stride 193 f4 => rows 4 apart alias; unfixable by padding)
//          from the critical-path h-GEMM. x-part W stays in LDS: its reads
//          run in the flag-wait slack, latency-hidden.
__global__ __launch_bounds__(512) __attribute__((amdgpu_waves_per_eu(2, 2)))
void lstm_persistent(const float* __restrict__ x,
                     const float* __restrict__ Wf, const float* __restrict__ bfp,
                     const float* __restrict__ Wi, const float* __restrict__ bip,
                     const float* __restrict__ Wg, const float* __restrict__ bgp,
                     const float* __restrict__ Wo, const float* __restrict__ bop,
                     float* __restrict__ out, unsigned* __restrict__ flag_ws) {
    __shared__ float4 W4[32 * S4];        // 32 rows x 768 fp32
    __shared__ float4 C4[16 * S4];        // combined [x|h] for 16 b
    __shared__ float  gates_s[16 * 33];
    __shared__ float  bias_s[32];

    const int tid = threadIdx.x;
    const int wg  = blockIdx.x;
    const int bgroup = (wg & 7) >> 1;                  // 0..3
    const int kslice = ((wg >> 3) << 1) | (wg & 1);    // 0..63
    const int bg0 = bgroup * 16;
    const int k0  = kslice * 8;

    // 64 flags per bgroup, packed 256 B (one wave-instruction covers all 64)
    unsigned* const flags = flag_ws + bgroup * NPROD;

    // ---- one-time: stage 32 weight rows (gate*8 + unit) into LDS ----
    {
        const int r    = tid >> 4;     // 0..31
        const int c0   = tid & 15;
        const int gate = r >> 3;
        const int unit = k0 + (r & 7);
        const float* wsrc = (gate == 0) ? Wf : (gate == 1) ? Wi : (gate == 2) ? Wg : Wo;
        const float4* src4 = (const float4*)(wsrc + (size_t)unit * KDIM);
        #pragma unroll 2
        for (int m = 0; m < 12; ++m)
            W4[r * S4 + c0 + 16 * m] = src4[c0 + 16 * m];
        if (tid < 32) {
            const int g2 = tid >> 3;
            const float* bsrc = (g2 == 0) ? bfp : (g2 == 1) ? bip : (g2 == 2) ? bgp : bop;
            bias_s[tid] = bsrc[k0 + (tid & 7)];
        }
    }

    float* const hx_sec = out + (size_t)T_STEPS * BATCH * HID;  // buf0 (ends as hx)
    float* const cx_sec = hx_sec + BATCH * HID;                 // buf1 (ends as cx)

    const int lb2 = tid >> 3;   // cell-update mapping (tid<128)
    const int u2  = tid & 7;

    // zero h0 slab via bypass stores; publish flag=1. __syncthreads drains
    // vmcnt(0) before s_barrier -> h stores visible before the flag store.
    if (tid < 128)
        store_bypass(&hx_sec[(size_t)(bg0 + lb2) * HID + (k0 + u2)], 0.0f);
    __syncthreads();     // also orders W4 staging before the wreg reads below
    if (tid == 0)
        store_flag(&flags[kslice], 1u);

    // GEMM mapping: lane strip over K (16 interleaved f4 stripes), 4x4 tile
    const int lbg = tid >> 7;        // 0..3  -> batches lbg*4..+3
    const int rg  = (tid >> 4) & 7;  // 0..7  -> rows rg*4..+3
    const int kq  = tid & 15;        // 0..15 -> K stripe

    // ---- one-time: h-part W fragments -> registers (128 VGPRs) ----
    // wreg[it*4+j] = W4[(rg*4+j)][kq + 16*(it+4)]  (K dwords 256..767)
    float4 wreg[32];
    #pragma unroll
    for (int it = 0; it < 8; ++it)
        #pragma unroll
        for (int j = 0; j < 4; ++j)
            wreg[it * 4 + j] = W4[(rg * 4 + j) * S4 + kq + 16 * (it + 4)];

    float c_reg = 0.0f;

    for (int t = 0; t < T_STEPS; ++t) {
        const float* h_read  = (t & 1) ? cx_sec : hx_sec;   // h_t in buf[t&1]
        float*       h_write = (t & 1) ? hx_sec : cx_sec;   // h_{t+1} -> buf[(t+1)&1]

        // ---- A: stage x_t (flag-independent; hides behind the poll) ----
        {
            const float4* xs = (const float4*)(x + ((size_t)t * BATCH + bg0) * DIN);
            #pragma unroll
            for (int m = 0; m < 2; ++m) {
                const int i4 = tid + 512 * m;               // 16b x 64 f4
                C4[(i4 >> 6) * S4 + (i4 & 63)] = xs[i4];
            }
        }
        __syncthreads();   // x staged; safe: previous D/E reads fenced above

        // ---- A2: x-part GEMM (K dwords 0..255) — independent of h_t ----
        // W for this part comes from LDS: these reads (and their 4-way
        // conflicts) execute in the flag-wait slack, off the critical path.
        float acc[4][4];
        #pragma unroll
        for (int i = 0; i < 4; ++i)
            #pragma unroll
            for (int j = 0; j < 4; ++j) acc[i][j] = 0.0f;

        #pragma unroll 2
        for (int it = 0; it < 4; ++it) {
            const int dq = kq + 16 * it;
            float4 cv[4], wv[4];
            #pragma unroll
            for (int i = 0; i < 4; ++i) cv[i] = C4[(lbg * 4 + i) * S4 + dq];
            #pragma unroll
            for (int j = 0; j < 4; ++j) wv[j] = W4[(rg * 4 + j) * S4 + dq];
            #pragma unroll
            for (int i = 0; i < 4; ++i) {
                #pragma unroll
                for (int j = 0; j < 4; ++j) {
                    acc[i][j] = fmaf(cv[i].x, wv[j].x, acc[i][j]);
                    acc[i][j] = fmaf(cv[i].y, wv[j].y, acc[i][j]);
                    acc[i][j] = fmaf(cv[i].z, wv[j].z, acc[i][j]);
                    acc[i][j] = fmaf(cv[i].w, wv[j].w, acc[i][j]);
                }
            }
        }

        // ---- B: wait until all 64 peers published h_t ----
        if (tid < 64) {
            const unsigned target = (unsigned)(t + 1);
            while (!__all((int)(load_flag(&flags[tid]) >= target)))
                __builtin_amdgcn_s_sleep(1);
        }
        __syncthreads();   // full barrier: gather can't hoist above

        // ---- C: gather h_t via bypass loads, full MLP (16 in flight) ----
        {
            const float* hsrc = h_read + (size_t)bg0 * HID;
            float hv[16];
            #pragma unroll
            for (int m = 0; m < 16; ++m)
                hv[m] = load_bypass(&hsrc[512 * m + tid]);
            float* Cf = (float*)C4;
            #pragma unroll
            for (int m = 0; m < 16; ++m)
                Cf[m * (S4 * 4) + 256 + tid] = hv[m];   // consecutive dwords: conflict-free
        }
        __syncthreads();

        // ---- D: h-part GEMM (K dwords 256..767) — W from REGISTERS ----
        // Only cv comes from LDS (16 distinct f4 per wave, broadcast across
        // rg => conflict-free). Full unroll keeps wreg indices static.
        #pragma unroll
        for (int it = 0; it < 8; ++it) {
            const int dq = kq + 16 * (it + 4);
            float4 cv[4];
            #pragma unroll
            for (int i = 0; i < 4; ++i) cv[i] = C4[(lbg * 4 + i) * S4 + dq];
            #pragma unroll
            for (int i = 0; i < 4; ++i) {
                #pragma unroll
                for (int j = 0; j < 4; ++j) {
                    const float4 w = wreg[it * 4 + j];
                    acc[i][j] = fmaf(cv[i].x, w.x, acc[i][j]);
                    acc[i][j] = fmaf(cv[i].y, w.y, acc[i][j]);
                    acc[i][j] = fmaf(cv[i].z, w.z, acc[i][j]);
                    acc[i][j] = fmaf(cv[i].w, w.w, acc[i][j]);
                }
            }
        }

        // ---- E: reduce 16 K-stripes via shuffle, park in LDS ----
        #pragma unroll
        for (int i = 0; i < 4; ++i) {
            #pragma unroll
            for (int j = 0; j < 4; ++j) {
                float v = acc[i][j];
                v += __shfl_xor(v, 1);
                v += __shfl_xor(v, 2);
                v += __shfl_xor(v, 4);
                v += __shfl_xor(v, 8);
                if (kq == 0)
                    gates_s[(lbg * 4 + i) * 33 + (rg * 4 + j)] = v;
            }
        }
        __syncthreads();

        // ---- F: LSTM cell update (one thread per (b, hidden unit)) ----
        if (tid < 128) {
            const float pf = gates_s[lb2 * 33 + u2]      + bias_s[u2];
            const float pi = gates_s[lb2 * 33 + 8 + u2]  + bias_s[8 + u2];
            const float pg = gates_s[lb2 * 33 + 16 + u2] + bias_s[16 + u2];
            const float po = gates_s[lb2 * 33 + 24 + u2] + bias_s[24 + u2];
            const float fg = fast_sigmoid(pf);
            const float ig = fast_sigmoid(pi);
            const float gg = fast_tanh(pg);
            const float og = fast_sigmoid(po);
            c_reg = fg * c_reg + ig * gg;
            const float h = og * fast_tanh(c_reg);
            const int b = bg0 + lb2;
            const int k = k0 + u2;
            store_bypass(&h_write[(size_t)b * HID + k], h);   // coherent-direct
            out[((size_t)t * BATCH + b) * HID + k] = h;       // cached, flushed at end
        }
        __syncthreads();   // drains vmcnt(0): h bypass stores globally visible

        // ---- G: publish h_{t+1}: one relaxed store, no RMW ----
        if (tid == 0)
            store_flag(&flags[kslice], (unsigned)(t + 2));
    }

    // Final: hx (h_512) already in hx_sec. Overwrite buf1 (h_511) with c only
    // after all peers finished step 511 (flag = 513 => done reading h_511).
    if (tid < 64) {
        const unsigned target = (unsigned)(T_STEPS + 1);
        while (!__all((int)(load_flag(&flags[tid]) >= target)))
            __builtin_amdgcn_s_sleep(1);
    }
    __syncthreads();
    if (tid < 128)
        cx_sec[(size_t)(bg0 + lb2) * HID + (k0 + u2)] = c_reg;
}

extern "C" void kernel_launch(void* const* d_in, const int* in_sizes, int n_in,
                              void* d_out, int out_size, void* d_ws, size_t ws_size,
                              hipStream_t stream) {
    (void)in_sizes; (void)n_in; (void)ws_size; (void)out_size;
    const float* x  = (const float*)d_in[0];
    const float* Wf = (const float*)d_in[1];
    const float* bf = (const float*)d_in[2];
    const float* Wi = (const float*)d_in[3];
    const float* bi = (const float*)d_in[4];
    const float* Wg = (const float*)d_in[5];
    const float* bg = (const float*)d_in[6];
    const float* Wo = (const float*)d_in[7];
    const float* bo = (const float*)d_in[8];
    float* out = (float*)d_out;
    unsigned* flags = (unsigned*)d_ws;

    // flags[4 bgroups][64 producers], 4B each; must start 0 (d_ws poisoned)
    hipMemsetAsync(d_ws, 0, 4 * NPROD * sizeof(unsigned), stream);

    void* args[] = {&x, &Wf, &bf, &Wi, &bi, &Wg, &bg, &Wo, &bo, &out, &flags};
    hipLaunchCooperativeKernel(reinterpret_cast<void*>(lstm_persistent),
                               dim3(NBLK), dim3(512), args, 0, stream);
}

// Round 6
// 5893.742 us; speedup vs baseline: 1.0231x; 1.0165x over previous
//
#include <hip/hip_runtime.h>

static constexpr int T_STEPS = 512;
static constexpr int BATCH   = 64;
static constexpr int DIN     = 256;
static constexpr int HID     = 512;
static constexpr int KDIM    = DIN + HID;   // 768
static constexpr int S4      = 193;         // LDS row stride in float4 (192 data + 1 pad)
static constexpr int NBLK    = 256;
static constexpr int NPROD   = 64;          // producers (kslices) per bgroup

__device__ __forceinline__ float fast_sigmoid(float v) {
    return 1.0f / (1.0f + __expf(-v));
}
__device__ __forceinline__ float fast_tanh(float v) {
    return 1.0f - 2.0f / (__expf(2.0f * v) + 1.0f);
}

// Relaxed agent-scope ops: L1+L2 bypass, served at the device coherence
// point. No buffer_wbl2 / buffer_inv anywhere (rounds 1-3 lesson: per-WG
// full-L2 writeback+invalidate is catastrophic).
__device__ __forceinline__ void store_bypass(float* p, float v) {
    __hip_atomic_store((unsigned int*)p, __float_as_uint(v),
                       __ATOMIC_RELAXED, __HIP_MEMORY_SCOPE_AGENT);
}
__device__ __forceinline__ float load_bypass(const float* p) {
    return __uint_as_float(__hip_atomic_load((const unsigned int*)p,
                           __ATOMIC_RELAXED, __HIP_MEMORY_SCOPE_AGENT));
}
__device__ __forceinline__ void store_flag(unsigned* p, unsigned v) {
    __hip_atomic_store(p, v, __ATOMIC_RELAXED, __HIP_MEMORY_SCOPE_AGENT);
}
__device__ __forceinline__ unsigned load_flag(const unsigned* p) {
    return __hip_atomic_load(p, __ATOMIC_RELAXED, __HIP_MEMORY_SCOPE_AGENT);
}

// ROUND 7: per-producer flags (relaxed stores) + wave-wide __all poll;
//          x-part GEMM hoisted above the wait (hides in the poll slack).
// ROUND 8/9: full h-part W (128 VGPRs) in registers REGRESSED (6030us):
//          allocator caps this kernel at 128 VGPRs regardless of
//          launch-bounds/waves_per_eu attributes — wreg spilled to scratch;
//          per-step scratch reloads doubled step latency (WRITE_SIZE
//          135->295MB). LESSON: design INSIDE the 128-VGPR budget.
// ROUND 10/11: R4/R5 benches died with container-level failures (no pytest
//          result, no profile) — infra, not kernel, is the leading theory;
//          sync protocol is byte-identical to R1/R3 which passed. This
//          round: same design, but attributes reverted to R1's exact
//          __launch_bounds__(512, 1) — the wreg=16 design fits in 128
//          VGPRs by construction and needs no occupancy attribute.
//          Cache HALF the h-part W (16 float4 = 64 VGPRs, K-iters 4..7);
//          iters 8..11 keep reading W from LDS. Essential live ~100 VGPRs
//          < 128 -> no scratch. Critical-path LDS reads/thread: 96 -> 80,
//          wv conflict population 48 -> 32. All wreg indices compile-time.
__global__ __launch_bounds__(512, 1)
void lstm_persistent(const float* __restrict__ x,
                     const float* __restrict__ Wf, const float* __restrict__ bfp,
                     const float* __restrict__ Wi, const float* __restrict__ bip,
                     const float* __restrict__ Wg, const float* __restrict__ bgp,
                     const float* __restrict__ Wo, const float* __restrict__ bop,
                     float* __restrict__ out, unsigned* __restrict__ flag_ws) {
    __shared__ float4 W4[32 * S4];        // 32 rows x 768 fp32
    __shared__ float4 C4[16 * S4];        // combined [x|h] for 16 b
    __shared__ float  gates_s[16 * 33];
    __shared__ float  bias_s[32];

    const int tid = threadIdx.x;
    const int wg  = blockIdx.x;
    const int bgroup = (wg & 7) >> 1;                  // 0..3
    const int kslice = ((wg >> 3) << 1) | (wg & 1);    // 0..63
    const int bg0 = bgroup * 16;
    const int k0  = kslice * 8;

    // 64 flags per bgroup, packed 256 B (one wave-instruction covers all 64)
    unsigned* const flags = flag_ws + bgroup * NPROD;

    // ---- one-time: stage 32 weight rows (gate*8 + unit) into LDS ----
    {
        const int r    = tid >> 4;     // 0..31
        const int c0   = tid & 15;
        const int gate = r >> 3;
        const int unit = k0 + (r & 7);
        const float* wsrc = (gate == 0) ? Wf : (gate == 1) ? Wi : (gate == 2) ? Wg : Wo;
        const float4* src4 = (const float4*)(wsrc + (size_t)unit * KDIM);
        #pragma unroll 2
        for (int m = 0; m < 12; ++m)
            W4[r * S4 + c0 + 16 * m] = src4[c0 + 16 * m];
        if (tid < 32) {
            const int g2 = tid >> 3;
            const float* bsrc = (g2 == 0) ? bfp : (g2 == 1) ? bip : (g2 == 2) ? bgp : bop;
            bias_s[tid] = bsrc[k0 + (tid & 7)];
        }
    }

    float* const hx_sec = out + (size_t)T_STEPS * BATCH * HID;  // buf0 (ends as hx)
    float* const cx_sec = hx_sec + BATCH * HID;                 // buf1 (ends as cx)

    const int lb2 = tid >> 3;   // cell-update mapping (tid<128)
    const int u2  = tid & 7;

    // zero h0 slab via bypass stores; publish flag=1. __syncthreads drains
    // vmcnt(0) before s_barrier -> h stores visible before the flag store.
    if (tid < 128)
        store_bypass(&hx_sec[(size_t)(bg0 + lb2) * HID + (k0 + u2)], 0.0f);
    __syncthreads();     // also orders W4 staging before the wreg reads below
    if (tid == 0)
        store_flag(&flags[kslice], 1u);

    // GEMM mapping: lane strip over K (16 interleaved f4 stripes), 4x4 tile
    const int lbg = tid >> 7;        // 0..3  -> batches lbg*4..+3
    const int rg  = (tid >> 4) & 7;  // 0..7  -> rows rg*4..+3
    const int kq  = tid & 15;        // 0..15 -> K stripe

    // ---- one-time: half of h-part W -> registers (16 f4 = 64 VGPRs) ----
    // wreg[it*4+j] = W4[(rg*4+j)][kq + 16*(it+4)]  (K-iters 4..7)
    float4 wreg[16];
    #pragma unroll
    for (int it = 0; it < 4; ++it)
        #pragma unroll
        for (int j = 0; j < 4; ++j)
            wreg[it * 4 + j] = W4[(rg * 4 + j) * S4 + kq + 16 * (it + 4)];

    float c_reg = 0.0f;

    for (int t = 0; t < T_STEPS; ++t) {
        const float* h_read  = (t & 1) ? cx_sec : hx_sec;   // h_t in buf[t&1]
        float*       h_write = (t & 1) ? hx_sec : cx_sec;   // h_{t+1} -> buf[(t+1)&1]

        // ---- A: stage x_t (flag-independent; hides behind the poll) ----
        {
            const float4* xs = (const float4*)(x + ((size_t)t * BATCH + bg0) * DIN);
            #pragma unroll
            for (int m = 0; m < 2; ++m) {
                const int i4 = tid + 512 * m;               // 16b x 64 f4
                C4[(i4 >> 6) * S4 + (i4 & 63)] = xs[i4];
            }
        }
        __syncthreads();   // x staged; safe: previous D/E reads fenced above

        // ---- A2: x-part GEMM (K dwords 0..255) — independent of h_t ----
        // W for this part comes from LDS: these reads (and their 4-way
        // conflicts) execute in the flag-wait slack, off the critical path.
        float acc[4][4];
        #pragma unroll
        for (int i = 0; i < 4; ++i)
            #pragma unroll
            for (int j = 0; j < 4; ++j) acc[i][j] = 0.0f;

        #pragma unroll 2
        for (int it = 0; it < 4; ++it) {
            const int dq = kq + 16 * it;
            float4 cv[4], wv[4];
            #pragma unroll
            for (int i = 0; i < 4; ++i) cv[i] = C4[(lbg * 4 + i) * S4 + dq];
            #pragma unroll
            for (int j = 0; j < 4; ++j) wv[j] = W4[(rg * 4 + j) * S4 + dq];
            #pragma unroll
            for (int i = 0; i < 4; ++i) {
                #pragma unroll
                for (int j = 0; j < 4; ++j) {
                    acc[i][j] = fmaf(cv[i].x, wv[j].x, acc[i][j]);
                    acc[i][j] = fmaf(cv[i].y, wv[j].y, acc[i][j]);
                    acc[i][j] = fmaf(cv[i].z, wv[j].z, acc[i][j]);
                    acc[i][j] = fmaf(cv[i].w, wv[j].w, acc[i][j]);
                }
            }
        }

        // ---- B: wait until all 64 peers published h_t ----
        if (tid < 64) {
            const unsigned target = (unsigned)(t + 1);
            while (!__all((int)(load_flag(&flags[tid]) >= target)))
                __builtin_amdgcn_s_sleep(1);
        }
        __syncthreads();   // full barrier: gather can't hoist above

        // ---- C: gather h_t via bypass loads, full MLP (16 in flight) ----
        {
            const float* hsrc = h_read + (size_t)bg0 * HID;
            float hv[16];
            #pragma unroll
            for (int m = 0; m < 16; ++m)
                hv[m] = load_bypass(&hsrc[512 * m + tid]);
            float* Cf = (float*)C4;
            #pragma unroll
            for (int m = 0; m < 16; ++m)
                Cf[m * (S4 * 4) + 256 + tid] = hv[m];   // consecutive dwords: conflict-free
        }
        __syncthreads();

        // ---- D: h-part GEMM (K dwords 256..767) ----
        // Interleaved: reg-half (iters 4..7, W from wreg) and LDS-half
        // (iters 8..11, W from LDS). cv reads are broadcast across rg
        // (16 distinct f4 per wave) => conflict-free.
        #pragma unroll
        for (int it = 0; it < 4; ++it) {
            {   // reg-half: K-iter it+4
                const int dq = kq + 16 * (it + 4);
                float4 cv[4];
                #pragma unroll
                for (int i = 0; i < 4; ++i) cv[i] = C4[(lbg * 4 + i) * S4 + dq];
                #pragma unroll
                for (int i = 0; i < 4; ++i) {
                    #pragma unroll
                    for (int j = 0; j < 4; ++j) {
                        const float4 w = wreg[it * 4 + j];
                        acc[i][j] = fmaf(cv[i].x, w.x, acc[i][j]);
                        acc[i][j] = fmaf(cv[i].y, w.y, acc[i][j]);
                        acc[i][j] = fmaf(cv[i].z, w.z, acc[i][j]);
                        acc[i][j] = fmaf(cv[i].w, w.w, acc[i][j]);
                    }
                }
            }
            {   // LDS-half: K-iter it+8
                const int dq = kq + 16 * (it + 8);
                float4 cv[4], wv[4];
                #pragma unroll
                for (int i = 0; i < 4; ++i) cv[i] = C4[(lbg * 4 + i) * S4 + dq];
                #pragma unroll
                for (int j = 0; j < 4; ++j) wv[j] = W4[(rg * 4 + j) * S4 + dq];
                #pragma unroll
                for (int i = 0; i < 4; ++i) {
                    #pragma unroll
                    for (int j = 0; j < 4; ++j) {
                        acc[i][j] = fmaf(cv[i].x, wv[j].x, acc[i][j]);
                        acc[i][j] = fmaf(cv[i].y, wv[j].y, acc[i][j]);
                        acc[i][j] = fmaf(cv[i].z, wv[j].z, acc[i][j]);
                        acc[i][j] = fmaf(cv[i].w, wv[j].w, acc[i][j]);
                    }
                }
            }
        }

        // ---- E: reduce 16 K-stripes via shuffle, park in LDS ----
        #pragma unroll
        for (int i = 0; i < 4; ++i) {
            #pragma unroll
            for (int j = 0; j < 4; ++j) {
                float v = acc[i][j];
                v += __shfl_xor(v, 1);
                v += __shfl_xor(v, 2);
                v += __shfl_xor(v, 4);
                v += __shfl_xor(v, 8);
                if (kq == 0)
                    gates_s[(lbg * 4 + i) * 33 + (rg * 4 + j)] = v;
            }
        }
        __syncthreads();

        // ---- F: LSTM cell update (one thread per (b, hidden unit)) ----
        if (tid < 128) {
            const float pf = gates_s[lb2 * 33 + u2]      + bias_s[u2];
            const float pi = gates_s[lb2 * 33 + 8 + u2]  + bias_s[8 + u2];
            const float pg = gates_s[lb2 * 33 + 16 + u2] + bias_s[16 + u2];
            const float po = gates_s[lb2 * 33 + 24 + u2] + bias_s[24 + u2];
            const float fg = fast_sigmoid(pf);
            const float ig = fast_sigmoid(pi);
            const float gg = fast_tanh(pg);
            const float og = fast_sigmoid(po);
            c_reg = fg * c_reg + ig * gg;
            const float h = og * fast_tanh(c_reg);
            const int b = bg0 + lb2;
            const int k = k0 + u2;
            store_bypass(&h_write[(size_t)b * HID + k], h);   // coherent-direct
            out[((size_t)t * BATCH + b) * HID + k] = h;       // cached, flushed at end
        }
        __syncthreads();   // drains vmcnt(0): h bypass stores globally visible

        // ---- G: publish h_{t+1}: one relaxed store, no RMW ----
        if (tid == 0)
            store_flag(&flags[kslice], (unsigned)(t + 2));
    }

    // Final: hx (h_512) already in hx_sec. Overwrite buf1 (h_511) with c only
    // after all peers finished step 511 (flag = 513 => done reading h_511).
    if (tid < 64) {
        const unsigned target = (unsigned)(T_STEPS + 1);
        while (!__all((int)(load_flag(&flags[tid]) >= target)))
            __builtin_amdgcn_s_sleep(1);
    }
    __syncthreads();
    if (tid < 128)
        cx_sec[(size_t)(bg0 + lb2) * HID + (k0 + u2)] = c_reg;
}

extern "C" void kernel_launch(void* const* d_in, const int* in_sizes, int n_in,
                              void* d_out, int out_size, void* d_ws, size_t ws_size,
                              hipStream_t stream) {
    (void)in_sizes; (void)n_in; (void)ws_size; (void)out_size;
    const float* x  = (const float*)d_in[0];
    const float* Wf = (const float*)d_in[1];
    const float* bf = (const float*)d_in[2];
    const float* Wi = (const float*)d_in[3];
    const float* bi = (const float*)d_in[4];
    const float* Wg = (const float*)d_in[5];
    const float* bg = (const float*)d_in[6];
    const float* Wo = (const float*)d_in[7];
    const float* bo = (const float*)d_in[8];
    float* out = (float*)d_out;
    unsigned* flags = (unsigned*)d_ws;

    // flags[4 bgroups][64 producers], 4B each; must start 0 (d_ws poisoned)
    hipMemsetAsync(d_ws, 0, 4 * NPROD * sizeof(unsigned), stream);

    void* args[] = {&x, &Wf, &bf, &Wi, &bi, &Wg, &bg, &Wo, &bo, &out, &flags};
    hipLaunchCooperativeKernel(reinterpret_cast<void*>(lstm_persistent),
                               dim3(NBLK), dim3(512), args, 0, stream);
}

// Round 7
// 2766.102 us; speedup vs baseline: 2.1800x; 2.1307x over previous
//
#include <hip/hip_runtime.h>

static constexpr int T_STEPS = 512;
static constexpr int BATCH   = 64;
static constexpr int DIN     = 256;
static constexpr int HID     = 512;
static constexpr int KDIM    = DIN + HID;   // 768
static constexpr int S4      = 193;         // LDS row stride in float4 (192 data + 1 pad)
static constexpr int NBLK    = 256;
static constexpr int NPROD   = 64;          // producers (kslices) per bgroup

__device__ __forceinline__ float fast_sigmoid(float v) {
    return 1.0f / (1.0f + __expf(-v));
}
__device__ __forceinline__ float fast_tanh(float v) {
    return 1.0f - 2.0f / (__expf(2.0f * v) + 1.0f);
}

// Relaxed agent-scope ops: L1+L2 bypass, served at the device coherence
// point. No buffer_wbl2 / buffer_inv anywhere (rounds 1-3 lesson: per-WG
// full-L2 writeback+invalidate is catastrophic).
__device__ __forceinline__ void store_bypass(float* p, float v) {
    __hip_atomic_store((unsigned int*)p, __float_as_uint(v),
                       __ATOMIC_RELAXED, __HIP_MEMORY_SCOPE_AGENT);
}
__device__ __forceinline__ float load_bypass(const float* p) {
    return __uint_as_float(__hip_atomic_load((const unsigned int*)p,
                           __ATOMIC_RELAXED, __HIP_MEMORY_SCOPE_AGENT));
}
__device__ __forceinline__ void store_flag(unsigned* p, unsigned v) {
    __hip_atomic_store(p, v, __ATOMIC_RELAXED, __HIP_MEMORY_SCOPE_AGENT);
}
__device__ __forceinline__ unsigned load_flag(const unsigned* p) {
    return __hip_atomic_load(p, __ATOMIC_RELAXED, __HIP_MEMORY_SCOPE_AGENT);
}

// DPP-rotate add: v += lane_rotated(v). All-VALU (no LDS pipe). ctrl must
// be a literal: 0xB1 quad_perm[1,0,3,2] (xor1), 0x4E quad_perm[2,3,0,1]
// (xor2), 0x124 row_ror:4, 0x128 row_ror:8. ror4+ror8 after the quad
// butterflies give every lane the full 16-lane sum (rotation covers all
// four quads; direction-independent for a sum).
#define DPP_ADD(v, ctrl)                                                  \
    (v) += __uint_as_float(__builtin_amdgcn_update_dpp(                   \
        0u, __float_as_uint(v), (ctrl), 0xF, 0xF, true))

// ROUND 7: per-producer flags (relaxed stores) + wave-wide __all poll;
//          x-part GEMM hoisted above the wait (hides in the poll slack).
// ROUND 8-11 (dead end, documented): caching h-part W in registers (any
//          size >= 16 float4) spills — the allocator pins this kernel at
//          128 VGPRs regardless of launch_bounds/waves_per_eu, and spill
//          reload latency on the critical path costs ~2.4ms (WRITE_SIZE
//          135->295MB signature). LESSON: baseline live set ~88 leaves no
//          room; do NOT re-attempt W register caching on this structure.
// ROUND 12: LDS-pipe roofline attack. Per-step LDS budget at R1: 9216 cyc
//          ds_read_b128 + ~960 write/gather + 3072 cyc shuffle-reduce
//          (__shfl_xor = ds_swizzle) + 1587 conflict ~= 14.8k cyc ~= 6.2us
//          of the 6.94us step: LDS ~90% busy = the binding pipe, while
//          VALU idles at 62%. Fix: the 16-lane kq reduction is contiguous
//          within DPP rows of 16 -> do it entirely in VALU with 4 dpp-adds
//          (quad_perm xor1, xor2, row_ror:4, row_ror:8). Removes all 64
//          ds_swizzle per lane per step: -3072 LDS cyc/step/CU, +0 VGPR.
__global__ __launch_bounds__(512, 1)
void lstm_persistent(const float* __restrict__ x,
                     const float* __restrict__ Wf, const float* __restrict__ bfp,
                     const float* __restrict__ Wi, const float* __restrict__ bip,
                     const float* __restrict__ Wg, const float* __restrict__ bgp,
                     const float* __restrict__ Wo, const float* __restrict__ bop,
                     float* __restrict__ out, unsigned* __restrict__ flag_ws) {
    __shared__ float4 W4[32 * S4];        // 32 rows x 768 fp32
    __shared__ float4 C4[16 * S4];        // combined [x|h] for 16 b
    __shared__ float  gates_s[16 * 33];
    __shared__ float  bias_s[32];

    const int tid = threadIdx.x;
    const int wg  = blockIdx.x;
    const int bgroup = (wg & 7) >> 1;                  // 0..3
    const int kslice = ((wg >> 3) << 1) | (wg & 1);    // 0..63
    const int bg0 = bgroup * 16;
    const int k0  = kslice * 8;

    // 64 flags per bgroup, packed 256 B (one wave-instruction covers all 64)
    unsigned* const flags = flag_ws + bgroup * NPROD;

    // ---- one-time: stage 32 weight rows (gate*8 + unit) into LDS ----
    {
        const int r    = tid >> 4;     // 0..31
        const int c0   = tid & 15;
        const int gate = r >> 3;
        const int unit = k0 + (r & 7);
        const float* wsrc = (gate == 0) ? Wf : (gate == 1) ? Wi : (gate == 2) ? Wg : Wo;
        const float4* src4 = (const float4*)(wsrc + (size_t)unit * KDIM);
        #pragma unroll 2
        for (int m = 0; m < 12; ++m)
            W4[r * S4 + c0 + 16 * m] = src4[c0 + 16 * m];
        if (tid < 32) {
            const int g2 = tid >> 3;
            const float* bsrc = (g2 == 0) ? bfp : (g2 == 1) ? bip : (g2 == 2) ? bgp : bop;
            bias_s[tid] = bsrc[k0 + (tid & 7)];
        }
    }

    float* const hx_sec = out + (size_t)T_STEPS * BATCH * HID;  // buf0 (ends as hx)
    float* const cx_sec = hx_sec + BATCH * HID;                 // buf1 (ends as cx)

    const int lb2 = tid >> 3;   // cell-update mapping (tid<128)
    const int u2  = tid & 7;

    // zero h0 slab via bypass stores; publish flag=1. __syncthreads drains
    // vmcnt(0) before s_barrier -> h stores visible before the flag store.
    if (tid < 128)
        store_bypass(&hx_sec[(size_t)(bg0 + lb2) * HID + (k0 + u2)], 0.0f);
    __syncthreads();
    if (tid == 0)
        store_flag(&flags[kslice], 1u);

    // GEMM mapping: lane strip over K (16 interleaved f4 stripes), 4x4 tile
    const int lbg = tid >> 7;        // 0..3  -> batches lbg*4..+3
    const int rg  = (tid >> 4) & 7;  // 0..7  -> rows rg*4..+3
    const int kq  = tid & 15;        // 0..15 -> K stripe

    float c_reg = 0.0f;

    for (int t = 0; t < T_STEPS; ++t) {
        const float* h_read  = (t & 1) ? cx_sec : hx_sec;   // h_t in buf[t&1]
        float*       h_write = (t & 1) ? hx_sec : cx_sec;   // h_{t+1} -> buf[(t+1)&1]

        // ---- A: stage x_t (flag-independent; hides behind the poll) ----
        {
            const float4* xs = (const float4*)(x + ((size_t)t * BATCH + bg0) * DIN);
            #pragma unroll
            for (int m = 0; m < 2; ++m) {
                const int i4 = tid + 512 * m;               // 16b x 64 f4
                C4[(i4 >> 6) * S4 + (i4 & 63)] = xs[i4];
            }
        }
        __syncthreads();   // x staged; safe: previous D/E reads fenced above

        // ---- A2: x-part GEMM (K dwords 0..255) — independent of h_t ----
        float acc[4][4];
        #pragma unroll
        for (int i = 0; i < 4; ++i)
            #pragma unroll
            for (int j = 0; j < 4; ++j) acc[i][j] = 0.0f;

        #pragma unroll 2
        for (int it = 0; it < 4; ++it) {
            const int dq = kq + 16 * it;
            float4 cv[4], wv[4];
            #pragma unroll
            for (int i = 0; i < 4; ++i) cv[i] = C4[(lbg * 4 + i) * S4 + dq];
            #pragma unroll
            for (int j = 0; j < 4; ++j) wv[j] = W4[(rg * 4 + j) * S4 + dq];
            #pragma unroll
            for (int i = 0; i < 4; ++i) {
                #pragma unroll
                for (int j = 0; j < 4; ++j) {
                    acc[i][j] = fmaf(cv[i].x, wv[j].x, acc[i][j]);
                    acc[i][j] = fmaf(cv[i].y, wv[j].y, acc[i][j]);
                    acc[i][j] = fmaf(cv[i].z, wv[j].z, acc[i][j]);
                    acc[i][j] = fmaf(cv[i].w, wv[j].w, acc[i][j]);
                }
            }
        }

        // ---- B: wait until all 64 peers published h_t ----
        // wave 0: lane l watches producer l. One uncached load per lane per
        // poll -> 4x64B LLC reads per iteration, no RMW anywhere.
        if (tid < 64) {
            const unsigned target = (unsigned)(t + 1);
            while (!__all((int)(load_flag(&flags[tid]) >= target)))
                __builtin_amdgcn_s_sleep(1);
        }
        __syncthreads();   // full barrier: gather can't hoist above

        // ---- C: gather h_t via bypass loads, full MLP (16 in flight) ----
        {
            const float* hsrc = h_read + (size_t)bg0 * HID;
            float hv[16];
            #pragma unroll
            for (int m = 0; m < 16; ++m)
                hv[m] = load_bypass(&hsrc[512 * m + tid]);
            float* Cf = (float*)C4;
            #pragma unroll
            for (int m = 0; m < 16; ++m)
                Cf[m * (S4 * 4) + 256 + tid] = hv[m];   // consecutive dwords: conflict-free
        }
        __syncthreads();

        // ---- D: h-part GEMM (K dwords 256..767), 8 of 12 K-iterations ----
        // unroll 2: live set ~ acc(16) + 2x(cv+wv)(64) + addr < 128 VGPRs.
        #pragma unroll 2
        for (int it = 4; it < 12; ++it) {
            const int dq = kq + 16 * it;
            float4 cv[4], wv[4];
            #pragma unroll
            for (int i = 0; i < 4; ++i) cv[i] = C4[(lbg * 4 + i) * S4 + dq];
            #pragma unroll
            for (int j = 0; j < 4; ++j) wv[j] = W4[(rg * 4 + j) * S4 + dq];
            #pragma unroll
            for (int i = 0; i < 4; ++i) {
                #pragma unroll
                for (int j = 0; j < 4; ++j) {
                    acc[i][j] = fmaf(cv[i].x, wv[j].x, acc[i][j]);
                    acc[i][j] = fmaf(cv[i].y, wv[j].y, acc[i][j]);
                    acc[i][j] = fmaf(cv[i].z, wv[j].z, acc[i][j]);
                    acc[i][j] = fmaf(cv[i].w, wv[j].w, acc[i][j]);
                }
            }
        }

        // ---- E: reduce 16 K-stripes via DPP rotations (pure VALU) ----
        // Replaces 64 ds_swizzle/lane (LDS pipe, the binding resource)
        // with 64 v_add_f32_dpp (VALU, 62% idle). Every lane ends with
        // the full 16-lane sum; kq==0 parks it for F.
        #pragma unroll
        for (int i = 0; i < 4; ++i) {
            #pragma unroll
            for (int j = 0; j < 4; ++j) {
                float v = acc[i][j];
                DPP_ADD(v, 0xB1);    // quad_perm [1,0,3,2]  (xor 1)
                DPP_ADD(v, 0x4E);    // quad_perm [2,3,0,1]  (xor 2)
                DPP_ADD(v, 0x124);   // row_ror:4
                DPP_ADD(v, 0x128);   // row_ror:8
                if (kq == 0)
                    gates_s[(lbg * 4 + i) * 33 + (rg * 4 + j)] = v;
            }
        }
        __syncthreads();

        // ---- F: LSTM cell update (one thread per (b, hidden unit)) ----
        if (tid < 128) {
            const float pf = gates_s[lb2 * 33 + u2]      + bias_s[u2];
            const float pi = gates_s[lb2 * 33 + 8 + u2]  + bias_s[8 + u2];
            const float pg = gates_s[lb2 * 33 + 16 + u2] + bias_s[16 + u2];
            const float po = gates_s[lb2 * 33 + 24 + u2] + bias_s[24 + u2];
            const float fg = fast_sigmoid(pf);
            const float ig = fast_sigmoid(pi);
            const float gg = fast_tanh(pg);
            const float og = fast_sigmoid(po);
            c_reg = fg * c_reg + ig * gg;
            const float h = og * fast_tanh(c_reg);
            const int b = bg0 + lb2;
            const int k = k0 + u2;
            store_bypass(&h_write[(size_t)b * HID + k], h);   // coherent-direct
            out[((size_t)t * BATCH + b) * HID + k] = h;       // cached, flushed at end
        }
        __syncthreads();   // drains vmcnt(0): h bypass stores globally visible

        // ---- G: publish h_{t+1}: one relaxed store, no RMW ----
        if (tid == 0)
            store_flag(&flags[kslice], (unsigned)(t + 2));
    }

    // Final: hx (h_512) already in hx_sec. Overwrite buf1 (h_511) with c only
    // after all peers finished step 511 (flag = 513 => done reading h_511).
    if (tid < 64) {
        const unsigned target = (unsigned)(T_STEPS + 1);
        while (!__all((int)(load_flag(&flags[tid]) >= target)))
            __builtin_amdgcn_s_sleep(1);
    }
    __syncthreads();
    if (tid < 128)
        cx_sec[(size_t)(bg0 + lb2) * HID + (k0 + u2)] = c_reg;
}

extern "C" void kernel_launch(void* const* d_in, const int* in_sizes, int n_in,
                              void* d_out, int out_size, void* d_ws, size_t ws_size,
                              hipStream_t stream) {
    (void)in_sizes; (void)n_in; (void)ws_size; (void)out_size;
    const float* x  = (const float*)d_in[0];
    const float* Wf = (const float*)d_in[1];
    const float* bf = (const float*)d_in[2];
    const float* Wi = (const float*)d_in[3];
    const float* bi = (const float*)d_in[4];
    const float* Wg = (const float*)d_in[5];
    const float* bg = (const float*)d_in[6];
    const float* Wo = (const float*)d_in[7];
    const float* bo = (const float*)d_in[8];
    float* out = (float*)d_out;
    unsigned* flags = (unsigned*)d_ws;

    // flags[4 bgroups][64 producers], 4B each; must start 0 (d_ws poisoned)
    hipMemsetAsync(d_ws, 0, 4 * NPROD * sizeof(unsigned), stream);

    void* args[] = {&x, &Wf, &bf, &Wi, &bi, &Wg, &bg, &Wo, &bo, &out, &flags};
    hipLaunchCooperativeKernel(reinterpret_cast<void*>(lstm_persistent),
                               dim3(NBLK), dim3(512), args, 0, stream);
}

// Round 8
// 2658.278 us; speedup vs baseline: 2.2684x; 1.0406x over previous
//
#include <hip/hip_runtime.h>

static constexpr int T_STEPS = 512;
static constexpr int BATCH   = 64;
static constexpr int DIN     = 256;
static constexpr int HID     = 512;
static constexpr int KDIM    = DIN + HID;   // 768
static constexpr int S4      = 193;         // LDS row stride in float4 (192 data + 1 pad)
static constexpr int NBLK    = 256;
static constexpr int NPROD   = 64;          // producers (kslices) per bgroup

__device__ __forceinline__ float fast_sigmoid(float v) {
    return 1.0f / (1.0f + __expf(-v));
}
__device__ __forceinline__ float fast_tanh(float v) {
    return 1.0f - 2.0f / (__expf(2.0f * v) + 1.0f);
}

// Relaxed agent-scope ops: L1+L2 bypass, served at the device coherence
// point. No buffer_wbl2 / buffer_inv anywhere (rounds 1-3 lesson: per-WG
// full-L2 writeback+invalidate is catastrophic).
__device__ __forceinline__ void store_bypass(float* p, float v) {
    __hip_atomic_store((unsigned int*)p, __float_as_uint(v),
                       __ATOMIC_RELAXED, __HIP_MEMORY_SCOPE_AGENT);
}
__device__ __forceinline__ float load_bypass(const float* p) {
    return __uint_as_float(__hip_atomic_load((const unsigned int*)p,
                           __ATOMIC_RELAXED, __HIP_MEMORY_SCOPE_AGENT));
}
__device__ __forceinline__ void store_flag(unsigned* p, unsigned v) {
    __hip_atomic_store(p, v, __ATOMIC_RELAXED, __HIP_MEMORY_SCOPE_AGENT);
}
__device__ __forceinline__ unsigned load_flag(const unsigned* p) {
    return __hip_atomic_load(p, __ATOMIC_RELAXED, __HIP_MEMORY_SCOPE_AGENT);
}

// DPP-rotate add: v += lane_permuted(v). All-VALU (no LDS pipe). ctrl is a
// literal: 0xB1 quad_perm[1,0,3,2] (xor1), 0x4E quad_perm[2,3,0,1] (xor2),
// 0x124 row_ror:4, 0x128 row_ror:8 -> every lane holds its 16-lane row sum.
// 0x142 row_bcast15: lanes 16-31 (48-63) += lane 15 (47) -> lanes 16-31 of
// each 32-half hold the full 32-lane sum. bound_ctrl=1 zero-fills invalid
// source lanes (harmless: non-writer lanes only).
#define DPP_ADD(v, ctrl)                                                  \
    (v) += __uint_as_float(__builtin_amdgcn_update_dpp(                   \
        0u, __float_as_uint(v), (ctrl), 0xF, 0xF, true))

// ROUND 7:  per-producer flags + wave-wide __all poll; x-GEMM above wait.
// ROUND 8-11 (dead end): W-in-registers spills at any size >= 64 VGPRs;
//           allocator pins 128 VGPRs. Design INSIDE the 128 budget.
// ROUND 12: E-phase shuffle-reduce moved from LDS (ds_swizzle) to VALU DPP
//           rotations: 3555 -> 2766us. LDS-pipe model now verified: ~97%
//           busy = the binding pipe (768 read-instr x 12cyc + 1584 conflict
//           + ~1800 write cyc ~= 12.6k cyc/step/CU vs 5.4us step).
// ROUND 13: re-tile the GEMM 4x4/KQ16 -> 8x4/KQ32. Read count per thread =
//           192/tr (cv) + 192/tb (wv); wv are the expensive reads (64
//           distinct f4 + measured 4.1 extra conflict cyc each, linear in
//           count across R1/R2/R6). tb 4->8 halves wv: 48->24. acc 32 f32 +
//           12 f4 transients (unroll 1) ~= 104 VGPR < 128, no spill by
//           construction. Reduce = 5 DPP stages (adds row_bcast15); E
//           writes pack float4 (8 x b128, same write cost). New wv pattern
//           (2 rows 4 apart x 32 consecutive cols) has no 4-way aliasing.
__global__ __launch_bounds__(512, 1)
void lstm_persistent(const float* __restrict__ x,
                     const float* __restrict__ Wf, const float* __restrict__ bfp,
                     const float* __restrict__ Wi, const float* __restrict__ bip,
                     const float* __restrict__ Wg, const float* __restrict__ bgp,
                     const float* __restrict__ Wo, const float* __restrict__ bop,
                     float* __restrict__ out, unsigned* __restrict__ flag_ws) {
    __shared__ float4 W4[32 * S4];        // 32 rows x 768 fp32
    __shared__ float4 C4[16 * S4];        // combined [x|h] for 16 b
    __shared__ float4 gates4[16 * 9];     // gates [16 b][36 f stride]
    __shared__ float  bias_s[32];

    const int tid = threadIdx.x;
    const int wg  = blockIdx.x;
    const int bgroup = (wg & 7) >> 1;                  // 0..3
    const int kslice = ((wg >> 3) << 1) | (wg & 1);    // 0..63
    const int bg0 = bgroup * 16;
    const int k0  = kslice * 8;

    // 64 flags per bgroup, packed 256 B (one wave-instruction covers all 64)
    unsigned* const flags = flag_ws + bgroup * NPROD;

    // ---- one-time: stage 32 weight rows (gate*8 + unit) into LDS ----
    {
        const int r    = tid >> 4;     // 0..31
        const int c0   = tid & 15;
        const int gate = r >> 3;
        const int unit = k0 + (r & 7);
        const float* wsrc = (gate == 0) ? Wf : (gate == 1) ? Wi : (gate == 2) ? Wg : Wo;
        const float4* src4 = (const float4*)(wsrc + (size_t)unit * KDIM);
        #pragma unroll 2
        for (int m = 0; m < 12; ++m)
            W4[r * S4 + c0 + 16 * m] = src4[c0 + 16 * m];
        if (tid < 32) {
            const int g2 = tid >> 3;
            const float* bsrc = (g2 == 0) ? bfp : (g2 == 1) ? bip : (g2 == 2) ? bgp : bop;
            bias_s[tid] = bsrc[k0 + (tid & 7)];
        }
    }

    float* const hx_sec = out + (size_t)T_STEPS * BATCH * HID;  // buf0 (ends as hx)
    float* const cx_sec = hx_sec + BATCH * HID;                 // buf1 (ends as cx)

    const int lb2 = tid >> 3;   // cell-update mapping (tid<128)
    const int u2  = tid & 7;

    // zero h0 slab via bypass stores; publish flag=1. __syncthreads drains
    // vmcnt(0) before s_barrier -> h stores visible before the flag store.
    if (tid < 128)
        store_bypass(&hx_sec[(size_t)(bg0 + lb2) * HID + (k0 + u2)], 0.0f);
    __syncthreads();
    if (tid == 0)
        store_flag(&flags[kslice], 1u);

    // GEMM mapping: 32 K-stripes per reduction, 8x4 tile per thread.
    const int kq  = tid & 31;        // 0..31 -> K stripe
    const int rg  = (tid >> 5) & 7;  // 0..7  -> rows rg*4..+3
    const int lbg = tid >> 8;        // 0..1  -> batches lbg*8..+7

    float c_reg = 0.0f;

    for (int t = 0; t < T_STEPS; ++t) {
        const float* h_read  = (t & 1) ? cx_sec : hx_sec;   // h_t in buf[t&1]
        float*       h_write = (t & 1) ? hx_sec : cx_sec;   // h_{t+1} -> buf[(t+1)&1]

        // ---- A: stage x_t (flag-independent; hides behind the poll) ----
        {
            const float4* xs = (const float4*)(x + ((size_t)t * BATCH + bg0) * DIN);
            #pragma unroll
            for (int m = 0; m < 2; ++m) {
                const int i4 = tid + 512 * m;               // 16b x 64 f4
                C4[(i4 >> 6) * S4 + (i4 & 63)] = xs[i4];
            }
        }
        __syncthreads();   // x staged; safe: previous D/E reads fenced above

        // ---- A2: x-part GEMM (K dwords 0..255) — independent of h_t ----
        float acc[8][4];
        #pragma unroll
        for (int i = 0; i < 8; ++i)
            #pragma unroll
            for (int j = 0; j < 4; ++j) acc[i][j] = 0.0f;

        #pragma unroll 1
        for (int it = 0; it < 2; ++it) {
            const int dq = kq + 32 * it;
            float4 cv[8], wv[4];
            #pragma unroll
            for (int i = 0; i < 8; ++i) cv[i] = C4[(lbg * 8 + i) * S4 + dq];
            #pragma unroll
            for (int j = 0; j < 4; ++j) wv[j] = W4[(rg * 4 + j) * S4 + dq];
            #pragma unroll
            for (int i = 0; i < 8; ++i) {
                #pragma unroll
                for (int j = 0; j < 4; ++j) {
                    acc[i][j] = fmaf(cv[i].x, wv[j].x, acc[i][j]);
                    acc[i][j] = fmaf(cv[i].y, wv[j].y, acc[i][j]);
                    acc[i][j] = fmaf(cv[i].z, wv[j].z, acc[i][j]);
                    acc[i][j] = fmaf(cv[i].w, wv[j].w, acc[i][j]);
                }
            }
        }

        // ---- B: wait until all 64 peers published h_t ----
        // wave 0: lane l watches producer l. One uncached load per lane per
        // poll -> 4x64B LLC reads per iteration, no RMW anywhere.
        if (tid < 64) {
            const unsigned target = (unsigned)(t + 1);
            while (!__all((int)(load_flag(&flags[tid]) >= target)))
                __builtin_amdgcn_s_sleep(1);
        }
        __syncthreads();   // full barrier: gather can't hoist above

        // ---- C: gather h_t via bypass loads, full MLP (16 in flight) ----
        {
            const float* hsrc = h_read + (size_t)bg0 * HID;
            float hv[16];
            #pragma unroll
            for (int m = 0; m < 16; ++m)
                hv[m] = load_bypass(&hsrc[512 * m + tid]);
            float* Cf = (float*)C4;
            #pragma unroll
            for (int m = 0; m < 16; ++m)
                Cf[m * (S4 * 4) + 256 + tid] = hv[m];   // consecutive dwords: conflict-free
        }
        __syncthreads();

        // ---- D: h-part GEMM (K dwords 256..767), 4 K-iterations ----
        // unroll 1: live set acc(32) + cv(32) + wv(16) + addr < 128 VGPRs.
        #pragma unroll 1
        for (int it = 2; it < 6; ++it) {
            const int dq = kq + 32 * it;
            float4 cv[8], wv[4];
            #pragma unroll
            for (int i = 0; i < 8; ++i) cv[i] = C4[(lbg * 8 + i) * S4 + dq];
            #pragma unroll
            for (int j = 0; j < 4; ++j) wv[j] = W4[(rg * 4 + j) * S4 + dq];
            #pragma unroll
            for (int i = 0; i < 8; ++i) {
                #pragma unroll
                for (int j = 0; j < 4; ++j) {
                    acc[i][j] = fmaf(cv[i].x, wv[j].x, acc[i][j]);
                    acc[i][j] = fmaf(cv[i].y, wv[j].y, acc[i][j]);
                    acc[i][j] = fmaf(cv[i].z, wv[j].z, acc[i][j]);
                    acc[i][j] = fmaf(cv[i].w, wv[j].w, acc[i][j]);
                }
            }
        }

        // ---- E: reduce 32 K-stripes via DPP (pure VALU), pack f4 write ----
        // 4 row stages give all lanes their 16-lane sum; row_bcast15 folds
        // row0 into row1 -> lanes with (tid&31)==16 hold the 32-lane sum
        // and write 4 consecutive gate-rows as one ds_write_b128.
        {
            const bool writer = ((tid & 31) == 16);
            #pragma unroll
            for (int i = 0; i < 8; ++i) {
                float g0, g1, g2, g3;
                {
                    float v = acc[i][0];
                    DPP_ADD(v, 0xB1); DPP_ADD(v, 0x4E);
                    DPP_ADD(v, 0x124); DPP_ADD(v, 0x128);
                    DPP_ADD(v, 0x142); g0 = v;
                }
                {
                    float v = acc[i][1];
                    DPP_ADD(v, 0xB1); DPP_ADD(v, 0x4E);
                    DPP_ADD(v, 0x124); DPP_ADD(v, 0x128);
                    DPP_ADD(v, 0x142); g1 = v;
                }
                {
                    float v = acc[i][2];
                    DPP_ADD(v, 0xB1); DPP_ADD(v, 0x4E);
                    DPP_ADD(v, 0x124); DPP_ADD(v, 0x128);
                    DPP_ADD(v, 0x142); g2 = v;
                }
                {
                    float v = acc[i][3];
                    DPP_ADD(v, 0xB1); DPP_ADD(v, 0x4E);
                    DPP_ADD(v, 0x124); DPP_ADD(v, 0x128);
                    DPP_ADD(v, 0x142); g3 = v;
                }
                if (writer)
                    gates4[(lbg * 8 + i) * 9 + rg] = make_float4(g0, g1, g2, g3);
            }
        }
        __syncthreads();

        // ---- F: LSTM cell update (one thread per (b, hidden unit)) ----
        if (tid < 128) {
            const float* gf = (const float*)gates4;   // stride 36 floats/batch
            const float pf = gf[lb2 * 36 + u2]      + bias_s[u2];
            const float pi = gf[lb2 * 36 + 8 + u2]  + bias_s[8 + u2];
            const float pg = gf[lb2 * 36 + 16 + u2] + bias_s[16 + u2];
            const float po = gf[lb2 * 36 + 24 + u2] + bias_s[24 + u2];
            const float fg = fast_sigmoid(pf);
            const float ig = fast_sigmoid(pi);
            const float gg = fast_tanh(pg);
            const float og = fast_sigmoid(po);
            c_reg = fg * c_reg + ig * gg;
            const float h = og * fast_tanh(c_reg);
            const int b = bg0 + lb2;
            const int k = k0 + u2;
            store_bypass(&h_write[(size_t)b * HID + k], h);   // coherent-direct
            out[((size_t)t * BATCH + b) * HID + k] = h;       // cached, flushed at end
        }
        __syncthreads();   // drains vmcnt(0): h bypass stores globally visible

        // ---- G: publish h_{t+1}: one relaxed store, no RMW ----
        if (tid == 0)
            store_flag(&flags[kslice], (unsigned)(t + 2));
    }

    // Final: hx (h_512) already in hx_sec. Overwrite buf1 (h_511) with c only
    // after all peers finished step 511 (flag = 513 => done reading h_511).
    if (tid < 64) {
        const unsigned target = (unsigned)(T_STEPS + 1);
        while (!__all((int)(load_flag(&flags[tid]) >= target)))
            __builtin_amdgcn_s_sleep(1);
    }
    __syncthreads();
    if (tid < 128)
        cx_sec[(size_t)(bg0 + lb2) * HID + (k0 + u2)] = c_reg;
}

extern "C" void kernel_launch(void* const* d_in, const int* in_sizes, int n_in,
                              void* d_out, int out_size, void* d_ws, size_t ws_size,
                              hipStream_t stream) {
    (void)in_sizes; (void)n_in; (void)ws_size; (void)out_size;
    const float* x  = (const float*)d_in[0];
    const float* Wf = (const float*)d_in[1];
    const float* bf = (const float*)d_in[2];
    const float* Wi = (const float*)d_in[3];
    const float* bi = (const float*)d_in[4];
    const float* Wg = (const float*)d_in[5];
    const float* bg = (const float*)d_in[6];
    const float* Wo = (const float*)d_in[7];
    const float* bo = (const float*)d_in[8];
    float* out = (float*)d_out;
    unsigned* flags = (unsigned*)d_ws;

    // flags[4 bgroups][64 producers], 4B each; must start 0 (d_ws poisoned)
    hipMemsetAsync(d_ws, 0, 4 * NPROD * sizeof(unsigned), stream);

    void* args[] = {&x, &Wf, &bf, &Wi, &bi, &Wg, &bg, &Wo, &bo, &out, &flags};
    hipLaunchCooperativeKernel(reinterpret_cast<void*>(lstm_persistent),
                               dim3(NBLK), dim3(512), args, 0, stream);
}